// Round 5
// baseline (638.135 us; speedup 1.0000x reference)
//
#include <hip/hip_runtime.h>
#include <hip/hip_bf16.h>
#include <math.h>

// Problem constants (fixed by the reference)
#define NN 8192     // nodes
#define FF 16       // node features
#define HH 64       // hidden
#define GG 256      // graphs
#define LN_EPS 1e-3f
#define KSPLIT 16
#define KC (NN / KSPLIT)   // 512

typedef __bf16 bf16x8 __attribute__((ext_vector_type(8)));
typedef float  floatx4 __attribute__((ext_vector_type(4)));

__device__ __forceinline__ bf16x8 cvt_bf8(const float4 a0, const float4 a1) {
    bf16x8 r;
    r[0] = (__bf16)a0.x; r[1] = (__bf16)a0.y; r[2] = (__bf16)a0.z; r[3] = (__bf16)a0.w;
    r[4] = (__bf16)a1.x; r[5] = (__bf16)a1.y; r[6] = (__bf16)a1.z; r[7] = (__bf16)a1.w;
    return r;
}

// ---------------------------------------------------------------------------
// K1: Zt0 = (X @ W0)^T  (bf16, [64][8192]) ; also z = log1p(relu(X[:,0])),
//     segment-max of z via uint atomicMax (z >= 0 so bit-compare == float-compare)
// grid 2048 x 256
__global__ void k1_xw0(const float* __restrict__ X,
                       const float* __restrict__ W0,
                       const int* __restrict__ I,
                       __hip_bfloat16* __restrict__ Zt0,
                       float* __restrict__ zarr,
                       unsigned int* __restrict__ zmax_bits) {
    const int b = blockIdx.x, tid = threadIdx.x;
    const int lane = tid & 63;
    const int i = (b & 127) * 64 + lane;          // node
    const int n = ((b >> 7) << 2) + (tid >> 6);   // output column
    float s = 0.f;
#pragma unroll
    for (int m = 0; m < FF; ++m)
        s += X[i * FF + m] * W0[m * HH + n];
    Zt0[(size_t)n * NN + i] = __float2bfloat16(s);   // coalesced along i

    if (b < 128 && tid < 64) {
        const int ii = b * 64 + lane;
        float z = log1pf(fmaxf(X[ii * FF], 0.f));
        zarr[ii] = z;
        atomicMax(&zmax_bits[I[ii]], __float_as_uint(z));
    }
}

// ---------------------------------------------------------------------------
// K-split MFMA GEMM: Cpart[kb] = A_chunk[8192, KC](fp32->bf16) @ Z_chunk
// grid 2048 = 128 rowblocks x 16 ksplit; block 256 thr = 4 waves.
// Block covers 64 rows; wave w rows w*16..+15; 4 independent col-chains (64 cols).
// Software-pipelined: next iteration's A/B loads issued before current MFMAs.
// Each Cpart cell written exactly once (no atomics).
__global__ __launch_bounds__(256)
void k_gemm_split(const float* __restrict__ A,
                  const __hip_bfloat16* __restrict__ Zt,
                  float* __restrict__ Cpart) {
    const int tid  = threadIdx.x;
    const int wave = tid >> 6;
    const int lane = tid & 63;
    const int l16  = lane & 15;
    const int quad = lane >> 4;
    const int rb   = blockIdx.x & 127;
    const int kb   = blockIdx.x >> 7;
    const int row0 = rb * 64;
    const int k0   = kb * KC;

    const float* aptr = A + (size_t)(row0 + wave * 16 + l16) * NN + k0 + quad * 8;
    const __hip_bfloat16* bp0 = Zt + (size_t)(0 * 16 + l16) * NN + k0 + quad * 8;
    const __hip_bfloat16* bp1 = Zt + (size_t)(1 * 16 + l16) * NN + k0 + quad * 8;
    const __hip_bfloat16* bp2 = Zt + (size_t)(2 * 16 + l16) * NN + k0 + quad * 8;
    const __hip_bfloat16* bp3 = Zt + (size_t)(3 * 16 + l16) * NN + k0 + quad * 8;

    floatx4 acc0 = {0.f,0.f,0.f,0.f}, acc1 = {0.f,0.f,0.f,0.f};
    floatx4 acc2 = {0.f,0.f,0.f,0.f}, acc3 = {0.f,0.f,0.f,0.f};

    // prologue: first tile in registers
    float4 ca0 = *reinterpret_cast<const float4*>(aptr);
    float4 ca1 = *reinterpret_cast<const float4*>(aptr + 4);
    bf16x8 cb0 = *reinterpret_cast<const bf16x8*>(bp0);
    bf16x8 cb1 = *reinterpret_cast<const bf16x8*>(bp1);
    bf16x8 cb2 = *reinterpret_cast<const bf16x8*>(bp2);
    bf16x8 cb3 = *reinterpret_cast<const bf16x8*>(bp3);

#pragma unroll
    for (int k = 32; k < KC; k += 32) {
        // prefetch next tile (issued before current MFMAs -> stays in flight)
        const float4 na0 = *reinterpret_cast<const float4*>(aptr + k);
        const float4 na1 = *reinterpret_cast<const float4*>(aptr + k + 4);
        const bf16x8 nb0 = *reinterpret_cast<const bf16x8*>(bp0 + k);
        const bf16x8 nb1 = *reinterpret_cast<const bf16x8*>(bp1 + k);
        const bf16x8 nb2 = *reinterpret_cast<const bf16x8*>(bp2 + k);
        const bf16x8 nb3 = *reinterpret_cast<const bf16x8*>(bp3 + k);

        const bf16x8 af = cvt_bf8(ca0, ca1);
        acc0 = __builtin_amdgcn_mfma_f32_16x16x32_bf16(af, cb0, acc0, 0, 0, 0);
        acc1 = __builtin_amdgcn_mfma_f32_16x16x32_bf16(af, cb1, acc1, 0, 0, 0);
        acc2 = __builtin_amdgcn_mfma_f32_16x16x32_bf16(af, cb2, acc2, 0, 0, 0);
        acc3 = __builtin_amdgcn_mfma_f32_16x16x32_bf16(af, cb3, acc3, 0, 0, 0);

        ca0 = na0; ca1 = na1; cb0 = nb0; cb1 = nb1; cb2 = nb2; cb3 = nb3;
    }
    {
        const bf16x8 af = cvt_bf8(ca0, ca1);
        acc0 = __builtin_amdgcn_mfma_f32_16x16x32_bf16(af, cb0, acc0, 0, 0, 0);
        acc1 = __builtin_amdgcn_mfma_f32_16x16x32_bf16(af, cb1, acc1, 0, 0, 0);
        acc2 = __builtin_amdgcn_mfma_f32_16x16x32_bf16(af, cb2, acc2, 0, 0, 0);
        acc3 = __builtin_amdgcn_mfma_f32_16x16x32_bf16(af, cb3, acc3, 0, 0, 0);
    }

    // C/D layout: m = quad*4 + reg, n = l16 (HW-verified m89/m91)
    float* Cp = Cpart + (size_t)kb * NN * HH;
    const size_t rbase = (size_t)(row0 + wave * 16 + quad * 4);
#pragma unroll
    for (int r = 0; r < 4; ++r) {
        float* crow = Cp + (rbase + r) * HH + l16;
        crow[ 0] = acc0[r];
        crow[16] = acc1[r];
        crow[32] = acc2[r];
        crow[48] = acc3[r];
    }
}

// ---------------------------------------------------------------------------
// LN epilogue: sum KSPLIT partials, then out = LN(relu(sum + bias))*gamma+beta (+resid)
// block 256 -> 16 rows; grid 512
__global__ __launch_bounds__(256)
void k_ln(const float* __restrict__ Cpart,
          const float* __restrict__ bias,
          const float* __restrict__ gamma,
          const float* __restrict__ beta,
          const float* __restrict__ resid,   // nullptr for layer 0
          float* __restrict__ out) {
    const int tid = threadIdx.x;
    const int row = tid >> 4;
    const int c0  = (tid & 15) * 4;
    const size_t grow = (size_t)(blockIdx.x * 16 + row);

    float4 v4 = {0.f, 0.f, 0.f, 0.f};
#pragma unroll
    for (int s = 0; s < KSPLIT; ++s) {
        const float4 p = *reinterpret_cast<const float4*>(
            &Cpart[(size_t)s * NN * HH + grow * HH + c0]);
        v4.x += p.x; v4.y += p.y; v4.z += p.z; v4.w += p.w;
    }
    const float4 b4 = *reinterpret_cast<const float4*>(&bias[c0]);
    float v[4] = { fmaxf(v4.x + b4.x, 0.f), fmaxf(v4.y + b4.y, 0.f),
                   fmaxf(v4.z + b4.z, 0.f), fmaxf(v4.w + b4.w, 0.f) };
    float s = 0.f, ss = 0.f;
#pragma unroll
    for (int j = 0; j < 4; ++j) { s += v[j]; ss += v[j] * v[j]; }
#pragma unroll
    for (int m = 1; m < 16; m <<= 1) {
        s  += __shfl_xor(s,  m, 64);
        ss += __shfl_xor(ss, m, 64);
    }
    const float mean = s * (1.f / 64.f);
    const float var  = fmaxf(ss * (1.f / 64.f) - mean * mean, 0.f);
    const float inv  = rsqrtf(var + LN_EPS);
    const float4 g4  = *reinterpret_cast<const float4*>(&gamma[c0]);
    const float4 be4 = *reinterpret_cast<const float4*>(&beta[c0]);
    float4 o;
    o.x = (v[0] - mean) * inv * g4.x + be4.x;
    o.y = (v[1] - mean) * inv * g4.y + be4.y;
    o.z = (v[2] - mean) * inv * g4.z + be4.z;
    o.w = (v[3] - mean) * inv * g4.w + be4.w;
    if (resid) {
        const float4 r4 = *reinterpret_cast<const float4*>(&resid[grow * HH + c0]);
        o.x += r4.x; o.y += r4.y; o.z += r4.z; o.w += r4.w;
    }
    *reinterpret_cast<float4*>(&out[grow * HH + c0]) = o;
}

// ---------------------------------------------------------------------------
// K3: Zt1 = (h0 @ W1)^T  (bf16 [64][8192])   grid 2048 x 256
__global__ void k3_hw1(const float* __restrict__ h0,
                       const float* __restrict__ W1,
                       __hip_bfloat16* __restrict__ Zt1) {
    const int b = blockIdx.x, tid = threadIdx.x;
    const int lane = tid & 63;
    const int i = (b & 127) * 64 + lane;
    const int n = ((b >> 7) << 2) + (tid >> 6);
    float s = 0.f;
#pragma unroll 8
    for (int m = 0; m < HH; ++m)
        s += h0[(size_t)i * HH + m] * W1[m * HH + n];
    Zt1[(size_t)n * NN + i] = __float2bfloat16(s);
}

// ---------------------------------------------------------------------------
// K5: feat = h@Wf + bf ; attn = sigmoid(h@Wa + ba) ; g[I[i]] += feat*attn
// 4 nodes per block (one wave each).  grid 2048 x 256
__global__ __launch_bounds__(256)
void k5_pool(const float* __restrict__ h,
             const float* __restrict__ Wf, const float* __restrict__ bfv,
             const float* __restrict__ Wa, const float* __restrict__ bav,
             const int* __restrict__ I,
             float* __restrict__ g) {
    __shared__ float hrow[4][64];
    const int w = threadIdx.x >> 6, l = threadIdx.x & 63;
    const int node = blockIdx.x * 4 + w;
    hrow[w][l] = h[(size_t)node * HH + l];
    __syncthreads();
    float sf = bfv[l], sa = bav[l];
#pragma unroll 8
    for (int m = 0; m < HH; ++m) {
        const float hv = hrow[w][m];
        sf += hv * Wf[m * HH + l];
        sa += hv * Wa[m * HH + l];
    }
    const float attn = 1.f / (1.f + expf(-sa));
    atomicAdd(&g[(size_t)I[node] * HH + l], sf * attn);
}

// ---------------------------------------------------------------------------
// K6: zexp = exp(z - zmax[seg]); zsum[seg] += zexp; baryn[seg] += zexp * xyz
// grid 32 x 256
__global__ void k6_bary(const float* __restrict__ X,
                        const int* __restrict__ I,
                        const float* __restrict__ zarr,
                        const float* __restrict__ zmax,
                        float* __restrict__ zsum,
                        float* __restrict__ baryn) {
    const int i = blockIdx.x * 256 + threadIdx.x;
    const int seg = I[i];
    const float ze = expf(zarr[i] - zmax[seg]);
    atomicAdd(&zsum[seg], ze);
    atomicAdd(&baryn[seg * 3 + 0], ze * X[i * FF + 13]);
    atomicAdd(&baryn[seg * 3 + 1], ze * X[i * FF + 14]);
    atomicAdd(&baryn[seg * 3 + 2], ze * X[i * FF + 15]);
}

// ---------------------------------------------------------------------------
// K7: out[gi] = concat(g[gi], baryn[gi]/zsum[gi]) @ Wout + bout
// one wave per graph; grid 64 x 256. Output fp32.
__global__ void k7_out(const float* __restrict__ g,
                       const float* __restrict__ zsum,
                       const float* __restrict__ baryn,
                       const float* __restrict__ Wout,
                       const float* __restrict__ bout,
                       float* __restrict__ out) {
    const int w = threadIdx.x >> 6, lane = threadIdx.x & 63;
    const int gi = blockIdx.x * 4 + w;
    const float vg = g[(size_t)gi * HH + lane];
    const float zs = zsum[gi];
    const float invz = (zs > 0.f) ? (1.f / zs) : 0.f;
    const float extra = (lane < 3) ? baryn[gi * 3 + lane] * invz : 0.f;
#pragma unroll
    for (int d = 0; d < 3; ++d) {
        float p = vg * Wout[lane * 3 + d];
        if (lane < 3) p += extra * Wout[(64 + lane) * 3 + d];
#pragma unroll
        for (int m = 1; m < 64; m <<= 1) p += __shfl_xor(p, m, 64);
        if (lane == 0) out[gi * 3 + d] = p + bout[d];
    }
}

// ---------------------------------------------------------------------------
extern "C" void kernel_launch(void* const* d_in, const int* in_sizes, int n_in,
                              void* d_out, int out_size, void* d_ws, size_t ws_size,
                              hipStream_t stream) {
    const float* X   = (const float*)d_in[0];
    const float* A   = (const float*)d_in[1];
    const int*   I   = (const int*)d_in[2];
    const float* W0  = (const float*)d_in[3];
    const float* b0  = (const float*)d_in[4];
    const float* g0  = (const float*)d_in[5];
    const float* be0 = (const float*)d_in[6];
    const float* W1  = (const float*)d_in[7];
    const float* b1  = (const float*)d_in[8];
    const float* g1  = (const float*)d_in[9];
    const float* be1 = (const float*)d_in[10];
    const float* Wf  = (const float*)d_in[11];
    const float* bfv = (const float*)d_in[12];
    const float* Wa  = (const float*)d_in[13];
    const float* bav = (const float*)d_in[14];
    const float* Wo  = (const float*)d_in[15];
    const float* bo  = (const float*)d_in[16];

    char* ws = (char*)d_ws;
    // accumulators (zeroed): g[256*64], zmax[256], zsum[256], baryn[256*3]
    float* accr  = (float*)(ws);
    float* g     = accr;
    float* zmax  = accr + GG * HH;
    float* zsum  = zmax + GG;
    float* baryn = zsum + GG;
    const size_t memset_bytes = (size_t)(GG * HH + GG + GG + GG * 3) * sizeof(float);

    __hip_bfloat16* Zt0 = (__hip_bfloat16*)(ws + (1u << 20));   // 1 MiB
    __hip_bfloat16* Zt1 = (__hip_bfloat16*)(ws + (2u << 20));   // 1 MiB
    float* h0    = (float*)(ws + (3u << 20));                   // 2 MiB
    float* h     = (float*)(ws + (5u << 20));                   // 2 MiB
    float* zarr  = (float*)(ws + (7u << 20));                   // 32 KiB
    float* Cpart = (float*)(ws + (8u << 20));                   // 32 MiB (16 slices)

    hipMemsetAsync(accr, 0, memset_bytes, stream);

    k1_xw0<<<2048, 256, 0, stream>>>(X, W0, I, Zt0, zarr, (unsigned int*)zmax);
    k_gemm_split<<<2048, 256, 0, stream>>>(A, Zt0, Cpart);
    k_ln<<<512, 256, 0, stream>>>(Cpart, b0, g0, be0, nullptr, h0);
    k3_hw1<<<2048, 256, 0, stream>>>(h0, W1, Zt1);
    k_gemm_split<<<2048, 256, 0, stream>>>(A, Zt1, Cpart);
    k_ln<<<512, 256, 0, stream>>>(Cpart, b1, g1, be1, h0, h);
    k5_pool<<<2048, 256, 0, stream>>>(h, Wf, bfv, Wa, bav, I, g);
    k6_bary<<<32, 256, 0, stream>>>(X, I, zarr, zmax, zsum, baryn);
    k7_out<<<64, 256, 0, stream>>>(g, zsum, baryn, Wo, bo, (float*)d_out);
}